// Round 19
// baseline (291.401 us; speedup 1.0000x reference)
//
#include <hip/hip_runtime.h>
#include <cmath>

static constexpr float NEG_SLOPE = 0.2f;
// two-level multisplit geometry (N=100000, E=1.6M, Et=1.7M)
static constexpr int CHUNK = 6144;     // edges per split1 block
static constexpr int NB1MAX = 112;     // coarse bins (1024 dsts each)
static constexpr int CAP1 = 20480;     // coarse bucket cap (mean 17.4K, +24 sigma)
static constexpr int SEG = 8;          // split2 segments per coarse bucket
static constexpr int LCAP2 = 512;      // LDS cap per fine bin in split2
static constexpr int CAP2 = 1664;      // fine bucket cap (mean 1088, +17 sigma)

typedef __attribute__((ext_vector_type(8))) short short8;   // 8 bf16 = 4 VGPR
typedef __attribute__((ext_vector_type(4))) float f32x4;
typedef __attribute__((ext_vector_type(2))) float f32x2;

// fp32 -> bf16 round-to-nearest-even (scalar; do NOT use cvt_pk asm — R15: -15us)
__device__ __forceinline__ short f2bf(float f) {
  unsigned u = __float_as_uint(f);
  unsigned r = (u + 0x7FFFu + ((u >> 16) & 1u)) >> 16;
  return (short)r;
}

// both weight transposes in one launch: W1[C][H]->Wt1[H][C], W2[H][64]->Wt2[64][H]
__global__ void transpose_cvt2(const float* __restrict__ W1, short* __restrict__ Wt1,
                               const float* __restrict__ W2, short* __restrict__ Wt2,
                               int C, int H) {
  int idx = blockIdx.x * blockDim.x + threadIdx.x;
  int n1 = C * H;
  if (idx < n1) {
    Wt1[(idx % H) * C + idx / H] = f2bf(W1[idx]);
  } else {
    int j = idx - n1;
    if (j < H * 64) Wt2[(j % 64) * H + j / 64] = f2bf(W2[j]);
  }
}

// ---- bf16-MFMA GEMM body: h[M,BN] = A[M,KTOT] * W[KTOT,BN], W transposed bf16.
// A fp32 (A_BF16=false) or bf16 (true). h written BF16. Fused s/d dots (fp32).
// R17 T14 prefetch, SINGLE buffer (R18 dbuf was neutral-negative: occupancy).
template<int BN, int KTOT, bool A_BF16>
__device__ __forceinline__
void gemm_body(int bid, const void* __restrict__ Av, const short* __restrict__ Bt,
               const float* __restrict__ a_s, const float* __restrict__ a_d,
               short* __restrict__ h, float* __restrict__ s,
               float* __restrict__ d, int M, char* smem) {
  constexpr int BM = 64, BK = 64;
  constexpr int NFRAG = BN / 16;
  constexpr int NB = (BN == 128) ? 4 : 2;
  char* As = smem;
  char* Bs = smem + 8192;

  const int tid = threadIdx.x;
  const int row0 = bid * BM;
  const int lane = tid & 63;
  const int w = tid >> 6;
  const int r15 = lane & 15, g = lane >> 4;

  const int arow = tid >> 2, aq = tid & 3;
  const int agr = row0 + arow;
  const int bcol = (BN == 128) ? (tid >> 1) : (tid >> 2);
  const int bq   = (BN == 128) ? (tid & 1)  : (tid & 3);

  f32x4 av[4];
  short8 as0, as1;
  short8 bv[NB];

  auto load_tile = [&](int k0) {
    if (A_BF16) {
      const short* A = (const short*)Av;
      if (agr < M) {
        const short* ap = A + (size_t)agr * KTOT + k0 + aq * 16;
        as0 = *reinterpret_cast<const short8*>(ap);
        as1 = *reinterpret_cast<const short8*>(ap + 8);
      } else {
        #pragma unroll
        for (int t = 0; t < 8; ++t) { as0[t] = 0; as1[t] = 0; }
      }
    } else {
      const float* A = (const float*)Av;
      if (agr < M) {
        const float* ap = A + (size_t)agr * KTOT + k0 + aq * 16;
        #pragma unroll
        for (int t = 0; t < 4; ++t)
          av[t] = *reinterpret_cast<const f32x4*>(ap + 4 * t);
      } else {
        #pragma unroll
        for (int t = 0; t < 4; ++t) av[t] = (f32x4)(0.f);
      }
    }
    const short* bp = Bt + (size_t)bcol * KTOT + k0 + bq * ((BN == 128) ? 32 : 16);
    #pragma unroll
    for (int t = 0; t < NB; ++t)
      bv[t] = *reinterpret_cast<const short8*>(bp + 8 * t);
  };

  auto store_tile = [&]() {
    short8 s0, s1;
    if (A_BF16) { s0 = as0; s1 = as1; }
    else {
      #pragma unroll
      for (int t = 0; t < 4; ++t) {
        s0[t]     = f2bf(av[0][t]); s0[4 + t] = f2bf(av[1][t]);
        s1[t]     = f2bf(av[2][t]); s1[4 + t] = f2bf(av[3][t]);
      }
    }
    int swz = (arow & 7) << 4;
    int b0 = arow * 128 + aq * 32;
    *reinterpret_cast<short8*>(As + (b0 ^ swz)) = s0;
    *reinterpret_cast<short8*>(As + ((b0 + 16) ^ swz)) = s1;
    int bswz = (bcol & 7) << 4;
    int bb0 = bcol * 128 + bq * ((BN == 128) ? 64 : 32);
    #pragma unroll
    for (int t = 0; t < NB; ++t)
      *reinterpret_cast<short8*>(Bs + ((bb0 + 16 * t) ^ bswz)) = bv[t];
  };

  f32x4 acc[NFRAG];
  #pragma unroll
  for (int j = 0; j < NFRAG; ++j) acc[j] = (f32x4)(0.f);

  load_tile(0);
  for (int k0 = 0; k0 < KTOT; k0 += BK) {
    store_tile();
    __syncthreads();
    if (k0 + BK < KTOT) load_tile(k0 + BK);   // in flight during MFMA
    #pragma unroll
    for (int kc = 0; kc < BK; kc += 32) {
      int ar = w * 16 + r15;
      short8 af = *reinterpret_cast<const short8*>(
          As + ((ar * 128 + (kc + g * 8) * 2) ^ ((r15 & 7) << 4)));
      #pragma unroll
      for (int j = 0; j < NFRAG; ++j) {
        int col = j * 16 + r15;
        short8 bf = *reinterpret_cast<const short8*>(
            Bs + ((col * 128 + (kc + g * 8) * 2) ^ ((r15 & 7) << 4)));
        acc[j] = __builtin_amdgcn_mfma_f32_16x16x32_bf16(af, bf, acc[j], 0, 0, 0);
      }
    }
    __syncthreads();
  }

  float ps[4] = {0.f, 0.f, 0.f, 0.f}, pd[4] = {0.f, 0.f, 0.f, 0.f};
  #pragma unroll
  for (int j = 0; j < NFRAG; ++j) {
    float asj = a_s[j * 16 + r15], adj = a_d[j * 16 + r15];
    #pragma unroll
    for (int r = 0; r < 4; ++r) {
      ps[r] = fmaf(acc[j][r], asj, ps[r]);
      pd[r] = fmaf(acc[j][r], adj, pd[r]);
    }
  }
  #pragma unroll
  for (int off = 1; off < 16; off <<= 1) {
    #pragma unroll
    for (int r = 0; r < 4; ++r) {
      ps[r] += __shfl_xor(ps[r], off);
      pd[r] += __shfl_xor(pd[r], off);
    }
  }
  #pragma unroll
  for (int r = 0; r < 4; ++r) {
    int gr = row0 + w * 16 + g * 4 + r;
    if (gr < M) {
      #pragma unroll
      for (int j = 0; j < NFRAG; ++j)
        h[(size_t)gr * BN + j * 16 + r15] = f2bf(acc[j][r]);
      if (r15 == 0) { s[gr] = ps[r]; d[gr] = pd[r]; }
    }
  }
}

// ---------------- split1 body (count -> reserve -> direct place) --------------
__device__ __forceinline__
void split1_body(int bid, const int* __restrict__ ei, int E, int Et, int NB1,
                 int* __restrict__ cnt1, unsigned* __restrict__ rec1, char* smem) {
  int* lcnt = (int*)smem;
  int* base = lcnt + NB1MAX;
  int tid = threadIdx.x;
  for (int i = tid; i < NB1; i += 256) lcnt[i] = 0;
  __syncthreads();
  int e0 = bid * CHUNK;
  int e1 = min(e0 + CHUNK, Et);
  for (int e = e0 + tid; e < e1; e += 256) {
    int di = (e < E) ? ei[E + e] : (e - E);
    atomicAdd(&lcnt[di >> 10], 1);
  }
  __syncthreads();
  for (int i = tid; i < NB1; i += 256) {
    base[i] = atomicAdd(&cnt1[i], lcnt[i]);
    lcnt[i] = 0;
  }
  __syncthreads();
  for (int e = e0 + tid; e < e1; e += 256) {
    int si, di;
    if (e < E) { si = ei[e]; di = ei[E + e]; }
    else       { si = e - E; di = si; }
    int g = di >> 10;
    unsigned r = ((unsigned)si << 10) | (unsigned)(di & 1023);
    int p = atomicAdd(&lcnt[g], 1);
    __builtin_nontemporal_store(r, rec1 + (size_t)g * CAP1 + base[g] + p);
  }
}

// fused: blocks [0,NS) run split1, rest run layer-1 GEMM (R13/R17 config)
template<int BN, int KTOT, bool A_BF16>
__launch_bounds__(256)
__global__ void fused_split_gemm(const int* __restrict__ ei, int E, int Et, int NB1,
                                 int* __restrict__ cnt1, unsigned* __restrict__ rec1,
                                 int NS, const void* __restrict__ Av,
                                 const short* __restrict__ Bt,
                                 const float* __restrict__ a_s,
                                 const float* __restrict__ a_d,
                                 short* __restrict__ h, float* __restrict__ s,
                                 float* __restrict__ d, int M) {
  __shared__ char smem[8192 + BN * 128];
  if ((int)blockIdx.x < NS)
    split1_body(blockIdx.x, ei, E, Et, NB1, cnt1, rec1, smem);
  else
    gemm_body<BN, KTOT, A_BF16>(blockIdx.x - NS, Av, Bt, a_s, a_d, h, s, d, M, smem);
}

// standalone GEMM (layer 2)
template<int BN, int KTOT, bool A_BF16>
__launch_bounds__(256)
__global__ void gemm_mfma(const void* __restrict__ Av, const short* __restrict__ Bt,
                          const float* __restrict__ a_s, const float* __restrict__ a_d,
                          short* __restrict__ h, float* __restrict__ s,
                          float* __restrict__ d, int M) {
  __shared__ char smem[8192 + BN * 128];
  gemm_body<BN, KTOT, A_BF16>(blockIdx.x, Av, Bt, a_s, a_d, h, s, d, M, smem);
}

// level 2: each coarse bucket -> 16 fine bins of 64 dsts. rec2 = (src<<6)|(dst&63)
__global__ void split2(const unsigned* __restrict__ rec1, const int* __restrict__ cnt1,
                       int* __restrict__ cnt2, unsigned* __restrict__ rec2) {
  __shared__ unsigned bins[16 * LCAP2];
  __shared__ int lcnt[16], base[16];
  int g1 = blockIdx.x / SEG, seg = blockIdx.x % SEG;
  int cnt = cnt1[g1];
  int len = (cnt + SEG - 1) / SEG;
  int lo = seg * len, hi = min(lo + len, cnt);
  int tid = threadIdx.x;
  if (tid < 16) lcnt[tid] = 0;
  __syncthreads();
  for (int i = lo + tid; i < hi; i += 256) {
    unsigned r = __builtin_nontemporal_load(rec1 + (size_t)g1 * CAP1 + i);
    int dloc = (int)(r & 1023u);
    int f = dloc >> 6;
    unsigned r2 = ((r >> 10) << 6) | (unsigned)(dloc & 63);
    int p = atomicAdd(&lcnt[f], 1);
    if (p < LCAP2) bins[f * LCAP2 + p] = r2;
    else {
      int gp = atomicAdd(&cnt2[g1 * 16 + f], 1);
      rec2[(size_t)(g1 * 16 + f) * CAP2 + gp] = r2;
    }
  }
  __syncthreads();
  if (tid < 16) {
    int c = min(lcnt[tid], LCAP2);
    lcnt[tid] = c;
    base[tid] = atomicAdd(&cnt2[g1 * 16 + tid], c);
  }
  __syncthreads();
  for (int f = 0; f < 16; ++f) {
    int c = lcnt[f], bs = base[f];
    for (int t = tid; t < c; t += 256)
      rec2[(size_t)(g1 * 16 + f) * CAP2 + bs + t] = bins[f * LCAP2 + t];
  }
}

// exclusive scan of cnt2[NB2] -> binbase; single block (NB2 <= 2048)
__global__ void scan_bins(const int* __restrict__ cnt2, int* __restrict__ binbase,
                          int NB2, int Et, int* __restrict__ row_ptr, int N) {
  __shared__ int part[256];
  __shared__ int vals[2048];
  int tid = threadIdx.x;
  int b0 = tid * 8;
  int lsum = 0;
  #pragma unroll
  for (int k = 0; k < 8; ++k) {
    int i = b0 + k;
    int v = (i < NB2) ? cnt2[i] : 0;
    vals[i] = lsum;
    lsum += v;
  }
  part[tid] = lsum;
  __syncthreads();
  for (int off = 1; off < 256; off <<= 1) {
    int t = (tid >= off) ? part[tid - off] : 0;
    __syncthreads();
    part[tid] += t;
    __syncthreads();
  }
  int pbase = part[tid] - lsum;
  #pragma unroll
  for (int k = 0; k < 8; ++k) {
    int i = b0 + k;
    if (i < NB2) binbase[i] = pbase + vals[i];
  }
  if (tid == 0) row_ptr[N] = Et;
}

// per-bin LDS counting sort -> exact CSR (row_ptr + col), all writes coalesced
__global__ void binsort(const unsigned* __restrict__ rec2, const int* __restrict__ cnt2,
                        const int* __restrict__ binbase, int* __restrict__ row_ptr,
                        int* __restrict__ col, int N) {
  __shared__ int cur[64];
  int bid = blockIdx.x;
  int dst0 = bid << 6;
  int cnt = cnt2[bid], base = binbase[bid];
  int tid = threadIdx.x;
  if (tid < 64) cur[tid] = 0;
  __syncthreads();
  const unsigned* rp = rec2 + (size_t)bid * CAP2;
  for (int i = tid; i < cnt; i += 256) atomicAdd(&cur[rp[i] & 63u], 1);
  __syncthreads();
  if (tid < 64) {
    int v = cur[tid];
    int x = v;
    #pragma unroll
    for (int off = 1; off < 64; off <<= 1) {
      int t = __shfl_up(x, off);
      if (tid >= off) x += t;
    }
    int excl = x - v;
    cur[tid] = excl;
    if (dst0 + tid < N) row_ptr[dst0 + tid] = base + excl;
  }
  __syncthreads();
  for (int i = tid; i < cnt; i += 256) {
    unsigned r = rp[i];
    int dl = (int)(r & 63u);
    int p = atomicAdd(&cur[dl], 1);
    col[base + p] = (int)(r >> 6);
  }
}

// ---------------- fused per-dst aggregation (one wave per dst) ----------------
// R19 MLP boost: GL halved (F=128: 8 lanes/group, F=64: 4), each lane covers
// 16 cols via 2x uint4 -> edges in flight x2, loads in flight x4 (16 / 32).
// No segment-max pass (softmax shift-invariance; leaky_relu bounds logits).
template<int F, int ACT, bool OUT_BF16>  // ACT: 0 relu, 1 sigmoid
__global__ void gat_aggregate(const int* __restrict__ row_ptr, const int* __restrict__ col,
                              const float* __restrict__ s, const float* __restrict__ d,
                              const short* __restrict__ hb, const float* __restrict__ b,
                              void* __restrict__ out, int N) {
  constexpr int GL = F / 16;         // lanes per group (8 or 4), 16 cols/lane
  constexpr int NG = 64 / GL;        // groups = edges in flight (8 or 16)
  // bijective XCD-chunk swizzle (m204)
  int nwg = gridDim.x, orig = blockIdx.x;
  int xcd = orig & 7, q = nwg >> 3, r = nwg & 7;
  int bs = (xcd < r ? xcd * (q + 1) : r * (q + 1) + (xcd - r) * q) + (orig >> 3);
  int wv = bs * 4 + ((int)threadIdx.x >> 6);
  int lane = threadIdx.x & 63;
  if (wv >= N) return;
  const int start = row_ptr[wv];
  const int end   = row_ptr[wv + 1];
  const float dd = d[wv];
  const int gl = lane % GL;          // 16-col slice within row
  const int g  = lane / GL;          // group id
  const short* hbase = hb + gl * 16;

  f32x2 acc2[8];
  #pragma unroll
  for (int t = 0; t < 8; ++t) { acc2[t][0] = 0.f; acc2[t][1] = 0.f; }
  float wsum = 0.f;

  auto body = [&](unsigned x, unsigned y, unsigned z, unsigned w_, float we, int base4) {
    f32x2 wv2; wv2[0] = we; wv2[1] = we;
    f32x2 p0, p1, p2, p3;
    p0[0] = __uint_as_float(x << 16); p0[1] = __uint_as_float(x & 0xFFFF0000u);
    p1[0] = __uint_as_float(y << 16); p1[1] = __uint_as_float(y & 0xFFFF0000u);
    p2[0] = __uint_as_float(z << 16); p2[1] = __uint_as_float(z & 0xFFFF0000u);
    p3[0] = __uint_as_float(w_ << 16); p3[1] = __uint_as_float(w_ & 0xFFFF0000u);
    acc2[base4 + 0] = __builtin_elementwise_fma(wv2, p0, acc2[base4 + 0]);
    acc2[base4 + 1] = __builtin_elementwise_fma(wv2, p1, acc2[base4 + 1]);
    acc2[base4 + 2] = __builtin_elementwise_fma(wv2, p2, acc2[base4 + 2]);
    acc2[base4 + 3] = __builtin_elementwise_fma(wv2, p3, acc2[base4 + 3]);
  };

  int c0 = start;
  // fast path: full 64-edge chunks, no guards
  for (; c0 + 64 <= end; c0 += 64) {
    int li = col[c0 + lane];
    float l = s[li] + dd;
    l = (l > 0.f) ? l : NEG_SLOPE * l;
    float w = __expf(l);
    wsum += w;
    int off = li * F;
    #pragma unroll 4
    for (int kk = 0; kk < 64; kk += NG) {
      int e = kk + g;
      float we = __shfl(w, e);
      int   oe = __shfl(off, e);
      uint4 v0 = *reinterpret_cast<const uint4*>(hbase + oe);
      uint4 v1 = *reinterpret_cast<const uint4*>(hbase + oe + 8);
      body(v0.x, v0.y, v0.z, v0.w, we, 0);
      body(v1.x, v1.y, v1.z, v1.w, we, 4);
    }
  }
  // tail chunk (guarded)
  if (c0 < end) {
    int j = c0 + lane;
    int li = (j < end) ? col[j] : 0;
    float w = 0.f;
    if (j < end) {
      float l = s[li] + dd;
      l = (l > 0.f) ? l : NEG_SLOPE * l;
      w = __expf(l);
    }
    wsum += w;
    int off = li * F;
    int nn = end - c0;
    for (int kk = 0; kk < nn; kk += NG) {
      int e = kk + g;
      float we = __shfl(w, e);
      int   oe = __shfl(off, e);
      if (e < nn) {
        uint4 v0 = *reinterpret_cast<const uint4*>(hbase + oe);
        uint4 v1 = *reinterpret_cast<const uint4*>(hbase + oe + 8);
        body(v0.x, v0.y, v0.z, v0.w, we, 0);
        body(v1.x, v1.y, v1.z, v1.w, we, 4);
      }
    }
  }
  // full-wave wsum reduce
  #pragma unroll
  for (int off = 32; off; off >>= 1) wsum += __shfl_xor(wsum, off);
  // cross-group acc reduce (lanes with same gl, different g)
  #pragma unroll
  for (int off = GL; off < 64; off <<= 1) {
    #pragma unroll
    for (int t = 0; t < 8; ++t) {
      acc2[t][0] += __shfl_xor(acc2[t][0], off);
      acc2[t][1] += __shfl_xor(acc2[t][1], off);
    }
  }
  float inv = 1.f / (wsum + 1e-16f);

  if (F == 128) {
    // NG=8: lane (g,gl) writes cols gl*16 + 2g, +1  (acc2[g])
    int c = gl * 16 + g * 2;
    float o0 = fmaf(acc2[g][0], inv, b[c]);
    float o1 = fmaf(acc2[g][1], inv, b[c + 1]);
    if (ACT == 0) { o0 = fmaxf(o0, 0.f); o1 = fmaxf(o1, 0.f); }
    else { o0 = 1.f / (1.f + __expf(-o0)); o1 = 1.f / (1.f + __expf(-o1)); }
    if (OUT_BF16) {
      unsigned p = ((unsigned)(unsigned short)f2bf(o1) << 16) | (unsigned short)f2bf(o0);
      reinterpret_cast<unsigned*>(out)[((size_t)wv * F + c) >> 1] = p;
    } else {
      reinterpret_cast<float2*>(out)[((size_t)wv * F + c) >> 1] = make_float2(o0, o1);
    }
  } else {
    // NG=16: lane (g,gl) writes col gl*16 + g  (acc2[g>>1][g&1])
    int c = gl * 16 + g;
    float av = (g & 1) ? acc2[g >> 1][1] : acc2[g >> 1][0];
    float o0 = fmaf(av, inv, b[c]);
    if (ACT == 0) o0 = fmaxf(o0, 0.f);
    else o0 = 1.f / (1.f + __expf(-o0));
    if (OUT_BF16) reinterpret_cast<short*>(out)[(size_t)wv * F + c] = f2bf(o0);
    else          reinterpret_cast<float*>(out)[(size_t)wv * F + c] = o0;
  }
}

extern "C" void kernel_launch(void* const* d_in, const int* in_sizes, int n_in,
                              void* d_out, int out_size, void* d_ws, size_t ws_size,
                              hipStream_t stream) {
  const int*   ei     = (const int*)d_in[0];
  const float* embed  = (const float*)d_in[1];
  const float* W1     = (const float*)d_in[2];
  const float* a_src1 = (const float*)d_in[3];
  const float* a_dst1 = (const float*)d_in[4];
  const float* b1     = (const float*)d_in[5];
  const float* W2     = (const float*)d_in[6];
  const float* a_src2 = (const float*)d_in[7];
  const float* a_dst2 = (const float*)d_in[8];
  const float* b2     = (const float*)d_in[9];

  const int E  = in_sizes[0] / 2;
  const int H  = in_sizes[3];          // 128
  const int C  = in_sizes[2] / H;      // 256
  const int N  = in_sizes[1] / C;      // 100000
  const int Et = E + N;
  const int NB1 = (N + 1023) >> 10;    // 98
  const int NB2 = NB1 << 4;            // 1568
  const int NS  = (Et + CHUNK - 1) / CHUNK;

  auto al16 = [](size_t x) { return (x + 15) & ~(size_t)15; };
  char* p = (char*)d_ws;
  short* hb = (short*)p;         p += al16((size_t)N * 128 * 2);
  short* xb = (short*)p;         p += al16((size_t)N * 128 * 2);
  float* sv = (float*)p;         p += al16((size_t)N * 4);
  float* dv = (float*)p;         p += al16((size_t)N * 4);
  int* row_ptr = (int*)p;        p += al16((size_t)(N + 1) * 4);
  int* col = (int*)p;            p += al16((size_t)Et * 4);
  int* cnt1 = (int*)p;           // cnt1 and cnt2 contiguous for one memset
  int* cnt2 = cnt1 + NB1;        p += al16((size_t)(NB1 + NB2) * 4);
  int* binbase = (int*)p;        p += al16((size_t)NB2 * 4);
  unsigned* rec1 = (unsigned*)p; p += al16((size_t)NB1 * CAP1 * 4);
  unsigned* rec2 = (unsigned*)p; p += al16((size_t)NB2 * CAP2 * 4);
  short* Wt1 = (short*)p;        p += al16((size_t)C * H * 2);
  short* Wt2 = (short*)p;

  dim3 blk(256);

  // ---------------- weight transposes (one launch) + counter clear ----------
  transpose_cvt2<<<dim3((C*H + H*64 + 255)/256), blk, 0, stream>>>(W1, Wt1, W2, Wt2, C, H);
  hipMemsetAsync(cnt1, 0, (size_t)(NB1 + NB2) * sizeof(int), stream);

  // ---------------- fused: split1 (CSR level 1) || layer-1 GEMM --------------
  fused_split_gemm<128, 256, false><<<dim3(NS + (N + 63)/64), blk, 0, stream>>>(
      ei, E, Et, NB1, cnt1, rec1, NS, embed, Wt1, a_src1, a_dst1, hb, sv, dv, N);

  // ---------------- CSR: split2 -> scan -> binsort ----------------
  split2<<<dim3(NB1 * SEG), blk, 0, stream>>>(rec1, cnt1, cnt2, rec2);
  scan_bins<<<dim3(1), blk, 0, stream>>>(cnt2, binbase, NB2, Et, row_ptr, N);
  binsort<<<dim3(NB2), blk, 0, stream>>>(rec2, cnt2, binbase, row_ptr, col, N);

  // ---------------- layer 1 aggregate ----------------
  gat_aggregate<128,0,true><<<dim3((N + 3)/4), blk, 0, stream>>>(row_ptr, col, sv, dv,
                                                                 hb, b1, xb, N);

  // ---------------- layer 2 ----------------
  gemm_mfma<64, 128, true><<<dim3((N + 63)/64), blk, 0, stream>>>(xb, Wt2, a_src2,
                                                                  a_dst2, hb, sv, dv, N);
  gat_aggregate<64,1,false><<<dim3((N + 3)/4), blk, 0, stream>>>(row_ptr, col, sv, dv,
                                                                 hb, b2, d_out, N);
}

// Round 20
// 230.613 us; speedup vs baseline: 1.2636x; 1.2636x over previous
//
#include <hip/hip_runtime.h>
#include <cmath>

static constexpr float NEG_SLOPE = 0.2f;
// two-level multisplit geometry (N=100000, E=1.6M, Et=1.7M)
static constexpr int CHUNK = 6144;     // edges per split1 block
static constexpr int NB1MAX = 112;     // coarse bins (1024 dsts each)
static constexpr int CAP1 = 20480;     // coarse bucket cap (mean 17.4K, +24 sigma)
static constexpr int SEG = 8;          // split2 segments per coarse bucket
static constexpr int LCAP2 = 512;      // LDS cap per fine bin in split2
static constexpr int CAP2 = 1664;      // fine bucket cap (mean 1088, +17 sigma)

typedef __attribute__((ext_vector_type(8))) short short8;   // 8 bf16 = 4 VGPR
typedef __attribute__((ext_vector_type(4))) float f32x4;
typedef __attribute__((ext_vector_type(2))) float f32x2;

// fp32 -> bf16 round-to-nearest-even (scalar; do NOT use cvt_pk asm — R15: -15us)
__device__ __forceinline__ short f2bf(float f) {
  unsigned u = __float_as_uint(f);
  unsigned r = (u + 0x7FFFu + ((u >> 16) & 1u)) >> 16;
  return (short)r;
}

// both weight transposes in one launch: W1[C][H]->Wt1[H][C], W2[H][64]->Wt2[64][H]
__global__ void transpose_cvt2(const float* __restrict__ W1, short* __restrict__ Wt1,
                               const float* __restrict__ W2, short* __restrict__ Wt2,
                               int C, int H) {
  int idx = blockIdx.x * blockDim.x + threadIdx.x;
  int n1 = C * H;
  if (idx < n1) {
    Wt1[(idx % H) * C + idx / H] = f2bf(W1[idx]);
  } else {
    int j = idx - n1;
    if (j < H * 64) Wt2[(j % 64) * H + j / 64] = f2bf(W2[j]);
  }
}

// ---- bf16-MFMA GEMM body: h[M,BN] = A[M,KTOT] * W[KTOT,BN], W transposed bf16.
// A fp32 (A_BF16=false) or bf16 (true). h written BF16. Fused s/d dots (fp32).
// R17 T14 prefetch, SINGLE buffer (R18 dbuf was neutral-negative: occupancy).
template<int BN, int KTOT, bool A_BF16>
__device__ __forceinline__
void gemm_body(int bid, const void* __restrict__ Av, const short* __restrict__ Bt,
               const float* __restrict__ a_s, const float* __restrict__ a_d,
               short* __restrict__ h, float* __restrict__ s,
               float* __restrict__ d, int M, char* smem) {
  constexpr int BM = 64, BK = 64;
  constexpr int NFRAG = BN / 16;
  constexpr int NB = (BN == 128) ? 4 : 2;
  char* As = smem;
  char* Bs = smem + 8192;

  const int tid = threadIdx.x;
  const int row0 = bid * BM;
  const int lane = tid & 63;
  const int w = tid >> 6;
  const int r15 = lane & 15, g = lane >> 4;

  const int arow = tid >> 2, aq = tid & 3;
  const int agr = row0 + arow;
  const int bcol = (BN == 128) ? (tid >> 1) : (tid >> 2);
  const int bq   = (BN == 128) ? (tid & 1)  : (tid & 3);

  f32x4 av[4];
  short8 as0, as1;
  short8 bv[NB];

  auto load_tile = [&](int k0) {
    if (A_BF16) {
      const short* A = (const short*)Av;
      if (agr < M) {
        const short* ap = A + (size_t)agr * KTOT + k0 + aq * 16;
        as0 = *reinterpret_cast<const short8*>(ap);
        as1 = *reinterpret_cast<const short8*>(ap + 8);
      } else {
        #pragma unroll
        for (int t = 0; t < 8; ++t) { as0[t] = 0; as1[t] = 0; }
      }
    } else {
      const float* A = (const float*)Av;
      if (agr < M) {
        const float* ap = A + (size_t)agr * KTOT + k0 + aq * 16;
        #pragma unroll
        for (int t = 0; t < 4; ++t)
          av[t] = *reinterpret_cast<const f32x4*>(ap + 4 * t);
      } else {
        #pragma unroll
        for (int t = 0; t < 4; ++t) av[t] = (f32x4)(0.f);
      }
    }
    const short* bp = Bt + (size_t)bcol * KTOT + k0 + bq * ((BN == 128) ? 32 : 16);
    #pragma unroll
    for (int t = 0; t < NB; ++t)
      bv[t] = *reinterpret_cast<const short8*>(bp + 8 * t);
  };

  auto store_tile = [&]() {
    short8 s0, s1;
    if (A_BF16) { s0 = as0; s1 = as1; }
    else {
      #pragma unroll
      for (int t = 0; t < 4; ++t) {
        s0[t]     = f2bf(av[0][t]); s0[4 + t] = f2bf(av[1][t]);
        s1[t]     = f2bf(av[2][t]); s1[4 + t] = f2bf(av[3][t]);
      }
    }
    int swz = (arow & 7) << 4;
    int b0 = arow * 128 + aq * 32;
    *reinterpret_cast<short8*>(As + (b0 ^ swz)) = s0;
    *reinterpret_cast<short8*>(As + ((b0 + 16) ^ swz)) = s1;
    int bswz = (bcol & 7) << 4;
    int bb0 = bcol * 128 + bq * ((BN == 128) ? 64 : 32);
    #pragma unroll
    for (int t = 0; t < NB; ++t)
      *reinterpret_cast<short8*>(Bs + ((bb0 + 16 * t) ^ bswz)) = bv[t];
  };

  f32x4 acc[NFRAG];
  #pragma unroll
  for (int j = 0; j < NFRAG; ++j) acc[j] = (f32x4)(0.f);

  load_tile(0);
  for (int k0 = 0; k0 < KTOT; k0 += BK) {
    store_tile();
    __syncthreads();
    if (k0 + BK < KTOT) load_tile(k0 + BK);   // in flight during MFMA
    #pragma unroll
    for (int kc = 0; kc < BK; kc += 32) {
      int ar = w * 16 + r15;
      short8 af = *reinterpret_cast<const short8*>(
          As + ((ar * 128 + (kc + g * 8) * 2) ^ ((r15 & 7) << 4)));
      #pragma unroll
      for (int j = 0; j < NFRAG; ++j) {
        int col = j * 16 + r15;
        short8 bf = *reinterpret_cast<const short8*>(
            Bs + ((col * 128 + (kc + g * 8) * 2) ^ ((r15 & 7) << 4)));
        acc[j] = __builtin_amdgcn_mfma_f32_16x16x32_bf16(af, bf, acc[j], 0, 0, 0);
      }
    }
    __syncthreads();
  }

  float ps[4] = {0.f, 0.f, 0.f, 0.f}, pd[4] = {0.f, 0.f, 0.f, 0.f};
  #pragma unroll
  for (int j = 0; j < NFRAG; ++j) {
    float asj = a_s[j * 16 + r15], adj = a_d[j * 16 + r15];
    #pragma unroll
    for (int r = 0; r < 4; ++r) {
      ps[r] = fmaf(acc[j][r], asj, ps[r]);
      pd[r] = fmaf(acc[j][r], adj, pd[r]);
    }
  }
  #pragma unroll
  for (int off = 1; off < 16; off <<= 1) {
    #pragma unroll
    for (int r = 0; r < 4; ++r) {
      ps[r] += __shfl_xor(ps[r], off);
      pd[r] += __shfl_xor(pd[r], off);
    }
  }
  #pragma unroll
  for (int r = 0; r < 4; ++r) {
    int gr = row0 + w * 16 + g * 4 + r;
    if (gr < M) {
      #pragma unroll
      for (int j = 0; j < NFRAG; ++j)
        h[(size_t)gr * BN + j * 16 + r15] = f2bf(acc[j][r]);
      if (r15 == 0) { s[gr] = ps[r]; d[gr] = pd[r]; }
    }
  }
}

// ---------------- split1 body (count -> reserve -> direct place) --------------
__device__ __forceinline__
void split1_body(int bid, const int* __restrict__ ei, int E, int Et, int NB1,
                 int* __restrict__ cnt1, unsigned* __restrict__ rec1, char* smem) {
  int* lcnt = (int*)smem;
  int* base = lcnt + NB1MAX;
  int tid = threadIdx.x;
  for (int i = tid; i < NB1; i += 256) lcnt[i] = 0;
  __syncthreads();
  int e0 = bid * CHUNK;
  int e1 = min(e0 + CHUNK, Et);
  for (int e = e0 + tid; e < e1; e += 256) {
    int di = (e < E) ? ei[E + e] : (e - E);
    atomicAdd(&lcnt[di >> 10], 1);
  }
  __syncthreads();
  for (int i = tid; i < NB1; i += 256) {
    base[i] = atomicAdd(&cnt1[i], lcnt[i]);
    lcnt[i] = 0;
  }
  __syncthreads();
  for (int e = e0 + tid; e < e1; e += 256) {
    int si, di;
    if (e < E) { si = ei[e]; di = ei[E + e]; }
    else       { si = e - E; di = si; }
    int g = di >> 10;
    unsigned r = ((unsigned)si << 10) | (unsigned)(di & 1023);
    int p = atomicAdd(&lcnt[g], 1);
    __builtin_nontemporal_store(r, rec1 + (size_t)g * CAP1 + base[g] + p);
  }
}

// fused: blocks [0,NS) run split1, rest run layer-1 GEMM (R13/R17 config)
template<int BN, int KTOT, bool A_BF16>
__launch_bounds__(256)
__global__ void fused_split_gemm(const int* __restrict__ ei, int E, int Et, int NB1,
                                 int* __restrict__ cnt1, unsigned* __restrict__ rec1,
                                 int NS, const void* __restrict__ Av,
                                 const short* __restrict__ Bt,
                                 const float* __restrict__ a_s,
                                 const float* __restrict__ a_d,
                                 short* __restrict__ h, float* __restrict__ s,
                                 float* __restrict__ d, int M) {
  __shared__ char smem[8192 + BN * 128];
  if ((int)blockIdx.x < NS)
    split1_body(blockIdx.x, ei, E, Et, NB1, cnt1, rec1, smem);
  else
    gemm_body<BN, KTOT, A_BF16>(blockIdx.x - NS, Av, Bt, a_s, a_d, h, s, d, M, smem);
}

// standalone GEMM (layer 2)
template<int BN, int KTOT, bool A_BF16>
__launch_bounds__(256)
__global__ void gemm_mfma(const void* __restrict__ Av, const short* __restrict__ Bt,
                          const float* __restrict__ a_s, const float* __restrict__ a_d,
                          short* __restrict__ h, float* __restrict__ s,
                          float* __restrict__ d, int M) {
  __shared__ char smem[8192 + BN * 128];
  gemm_body<BN, KTOT, A_BF16>(blockIdx.x, Av, Bt, a_s, a_d, h, s, d, M, smem);
}

// level 2: each coarse bucket -> 16 fine bins of 64 dsts. rec2 = (src<<6)|(dst&63)
__global__ void split2(const unsigned* __restrict__ rec1, const int* __restrict__ cnt1,
                       int* __restrict__ cnt2, unsigned* __restrict__ rec2) {
  __shared__ unsigned bins[16 * LCAP2];
  __shared__ int lcnt[16], base[16];
  int g1 = blockIdx.x / SEG, seg = blockIdx.x % SEG;
  int cnt = cnt1[g1];
  int len = (cnt + SEG - 1) / SEG;
  int lo = seg * len, hi = min(lo + len, cnt);
  int tid = threadIdx.x;
  if (tid < 16) lcnt[tid] = 0;
  __syncthreads();
  for (int i = lo + tid; i < hi; i += 256) {
    unsigned r = __builtin_nontemporal_load(rec1 + (size_t)g1 * CAP1 + i);
    int dloc = (int)(r & 1023u);
    int f = dloc >> 6;
    unsigned r2 = ((r >> 10) << 6) | (unsigned)(dloc & 63);
    int p = atomicAdd(&lcnt[f], 1);
    if (p < LCAP2) bins[f * LCAP2 + p] = r2;
    else {
      int gp = atomicAdd(&cnt2[g1 * 16 + f], 1);
      rec2[(size_t)(g1 * 16 + f) * CAP2 + gp] = r2;
    }
  }
  __syncthreads();
  if (tid < 16) {
    int c = min(lcnt[tid], LCAP2);
    lcnt[tid] = c;
    base[tid] = atomicAdd(&cnt2[g1 * 16 + tid], c);
  }
  __syncthreads();
  for (int f = 0; f < 16; ++f) {
    int c = lcnt[f], bs = base[f];
    for (int t = tid; t < c; t += 256)
      rec2[(size_t)(g1 * 16 + f) * CAP2 + bs + t] = bins[f * LCAP2 + t];
  }
}

// exclusive scan of cnt2[NB2] -> binbase; single block (NB2 <= 2048)
__global__ void scan_bins(const int* __restrict__ cnt2, int* __restrict__ binbase,
                          int NB2, int Et, int* __restrict__ row_ptr, int N) {
  __shared__ int part[256];
  __shared__ int vals[2048];
  int tid = threadIdx.x;
  int b0 = tid * 8;
  int lsum = 0;
  #pragma unroll
  for (int k = 0; k < 8; ++k) {
    int i = b0 + k;
    int v = (i < NB2) ? cnt2[i] : 0;
    vals[i] = lsum;
    lsum += v;
  }
  part[tid] = lsum;
  __syncthreads();
  for (int off = 1; off < 256; off <<= 1) {
    int t = (tid >= off) ? part[tid - off] : 0;
    __syncthreads();
    part[tid] += t;
    __syncthreads();
  }
  int pbase = part[tid] - lsum;
  #pragma unroll
  for (int k = 0; k < 8; ++k) {
    int i = b0 + k;
    if (i < NB2) binbase[i] = pbase + vals[i];
  }
  if (tid == 0) row_ptr[N] = Et;
}

// per-bin LDS counting sort -> exact CSR (row_ptr + col), all writes coalesced
__global__ void binsort(const unsigned* __restrict__ rec2, const int* __restrict__ cnt2,
                        const int* __restrict__ binbase, int* __restrict__ row_ptr,
                        int* __restrict__ col, int N) {
  __shared__ int cur[64];
  int bid = blockIdx.x;
  int dst0 = bid << 6;
  int cnt = cnt2[bid], base = binbase[bid];
  int tid = threadIdx.x;
  if (tid < 64) cur[tid] = 0;
  __syncthreads();
  const unsigned* rp = rec2 + (size_t)bid * CAP2;
  for (int i = tid; i < cnt; i += 256) atomicAdd(&cur[rp[i] & 63u], 1);
  __syncthreads();
  if (tid < 64) {
    int v = cur[tid];
    int x = v;
    #pragma unroll
    for (int off = 1; off < 64; off <<= 1) {
      int t = __shfl_up(x, off);
      if (tid >= off) x += t;
    }
    int excl = x - v;
    cur[tid] = excl;
    if (dst0 + tid < N) row_ptr[dst0 + tid] = base + excl;
  }
  __syncthreads();
  for (int i = tid; i < cnt; i += 256) {
    unsigned r = rp[i];
    int dl = (int)(r & 63u);
    int p = atomicAdd(&cur[dl], 1);
    col[base + p] = (int)(r >> 6);
  }
}

// ---------------- fused per-dst aggregation (one wave per dst) ----------------
// R16/R17 form (R19's GL-halving raised VGPR 20->52, occupancy 76->40%, -37us:
// for short rows TLP beats per-wave ILP — keep GL=F/8, acc2[4]).
// No segment-max pass (softmax shift-invariance; leaky_relu bounds logits).
template<int F, int ACT, bool OUT_BF16>  // ACT: 0 relu, 1 sigmoid
__global__ void gat_aggregate(const int* __restrict__ row_ptr, const int* __restrict__ col,
                              const float* __restrict__ s, const float* __restrict__ d,
                              const short* __restrict__ hb, const float* __restrict__ b,
                              void* __restrict__ out, int N) {
  constexpr int GL = F / 8;          // lanes per group (16 or 8)
  constexpr int NG = 64 / GL;        // groups = edges in flight (4 or 8)
  // bijective XCD-chunk swizzle (m204)
  int nwg = gridDim.x, orig = blockIdx.x;
  int xcd = orig & 7, q = nwg >> 3, r = nwg & 7;
  int bs = (xcd < r ? xcd * (q + 1) : r * (q + 1) + (xcd - r) * q) + (orig >> 3);
  int wv = bs * 4 + ((int)threadIdx.x >> 6);
  int lane = threadIdx.x & 63;
  if (wv >= N) return;
  const int start = row_ptr[wv];
  const int end   = row_ptr[wv + 1];
  const float dd = d[wv];
  const int gl = lane % GL;          // column-slot within group
  const int g  = lane / GL;          // group id
  const short* hbase = hb + gl * 8;

  f32x2 acc2[4];
  #pragma unroll
  for (int t = 0; t < 4; ++t) { acc2[t][0] = 0.f; acc2[t][1] = 0.f; }
  float wsum = 0.f;

  int c0 = start;
  // fast path: full 64-edge chunks, no guards
  for (; c0 + 64 <= end; c0 += 64) {
    int li = col[c0 + lane];
    float l = s[li] + dd;
    l = (l > 0.f) ? l : NEG_SLOPE * l;
    float w = __expf(l);
    wsum += w;
    int off = li * F;
    #pragma unroll 4
    for (int kk = 0; kk < 64; kk += NG) {
      int e = kk + g;
      float we = __shfl(w, e);
      int   oe = __shfl(off, e);
      uint4 v = *reinterpret_cast<const uint4*>(hbase + oe);
      f32x2 wv2; wv2[0] = we; wv2[1] = we;
      f32x2 p0, p1, p2, p3;
      p0[0] = __uint_as_float(v.x << 16); p0[1] = __uint_as_float(v.x & 0xFFFF0000u);
      p1[0] = __uint_as_float(v.y << 16); p1[1] = __uint_as_float(v.y & 0xFFFF0000u);
      p2[0] = __uint_as_float(v.z << 16); p2[1] = __uint_as_float(v.z & 0xFFFF0000u);
      p3[0] = __uint_as_float(v.w << 16); p3[1] = __uint_as_float(v.w & 0xFFFF0000u);
      acc2[0] = __builtin_elementwise_fma(wv2, p0, acc2[0]);
      acc2[1] = __builtin_elementwise_fma(wv2, p1, acc2[1]);
      acc2[2] = __builtin_elementwise_fma(wv2, p2, acc2[2]);
      acc2[3] = __builtin_elementwise_fma(wv2, p3, acc2[3]);
    }
  }
  // tail chunk (guarded)
  if (c0 < end) {
    int j = c0 + lane;
    int li = (j < end) ? col[j] : 0;
    float w = 0.f;
    if (j < end) {
      float l = s[li] + dd;
      l = (l > 0.f) ? l : NEG_SLOPE * l;
      w = __expf(l);
    }
    wsum += w;
    int off = li * F;
    int nn = end - c0;
    for (int kk = 0; kk < nn; kk += NG) {
      int e = kk + g;
      float we = __shfl(w, e);
      int   oe = __shfl(off, e);
      if (e < nn) {
        uint4 v = *reinterpret_cast<const uint4*>(hbase + oe);
        f32x2 wv2; wv2[0] = we; wv2[1] = we;
        f32x2 p0, p1, p2, p3;
        p0[0] = __uint_as_float(v.x << 16); p0[1] = __uint_as_float(v.x & 0xFFFF0000u);
        p1[0] = __uint_as_float(v.y << 16); p1[1] = __uint_as_float(v.y & 0xFFFF0000u);
        p2[0] = __uint_as_float(v.z << 16); p2[1] = __uint_as_float(v.z & 0xFFFF0000u);
        p3[0] = __uint_as_float(v.w << 16); p3[1] = __uint_as_float(v.w & 0xFFFF0000u);
        acc2[0] = __builtin_elementwise_fma(wv2, p0, acc2[0]);
        acc2[1] = __builtin_elementwise_fma(wv2, p1, acc2[1]);
        acc2[2] = __builtin_elementwise_fma(wv2, p2, acc2[2]);
        acc2[3] = __builtin_elementwise_fma(wv2, p3, acc2[3]);
      }
    }
  }
  // full-wave wsum reduce
  #pragma unroll
  for (int off = 32; off; off >>= 1) wsum += __shfl_xor(wsum, off);
  // cross-group acc reduce (groups hold partials for the same column slice)
  #pragma unroll
  for (int off = GL; off < 64; off <<= 1) {
    #pragma unroll
    for (int t = 0; t < 4; ++t) {
      acc2[t][0] += __shfl_xor(acc2[t][0], off);
      acc2[t][1] += __shfl_xor(acc2[t][1], off);
    }
  }
  float inv = 1.f / (wsum + 1e-16f);

  if (F == 128) {
    int c = gl * 8 + g * 2;
    float o0 = fmaf(acc2[g][0], inv, b[c]);
    float o1 = fmaf(acc2[g][1], inv, b[c + 1]);
    if (ACT == 0) { o0 = fmaxf(o0, 0.f); o1 = fmaxf(o1, 0.f); }
    else { o0 = 1.f / (1.f + __expf(-o0)); o1 = 1.f / (1.f + __expf(-o1)); }
    if (OUT_BF16) {
      unsigned p = ((unsigned)(unsigned short)f2bf(o1) << 16) | (unsigned short)f2bf(o0);
      reinterpret_cast<unsigned*>(out)[((size_t)wv * F + c) >> 1] = p;
    } else {
      reinterpret_cast<float2*>(out)[((size_t)wv * F + c) >> 1] = make_float2(o0, o1);
    }
  } else {
    int c = gl * 8 + g;
    float av = (g & 1) ? acc2[g >> 1][1] : acc2[g >> 1][0];
    float o0 = fmaf(av, inv, b[c]);
    if (ACT == 0) o0 = fmaxf(o0, 0.f);
    else o0 = 1.f / (1.f + __expf(-o0));
    if (OUT_BF16) reinterpret_cast<short*>(out)[(size_t)wv * F + c] = f2bf(o0);
    else          reinterpret_cast<float*>(out)[(size_t)wv * F + c] = o0;
  }
}

extern "C" void kernel_launch(void* const* d_in, const int* in_sizes, int n_in,
                              void* d_out, int out_size, void* d_ws, size_t ws_size,
                              hipStream_t stream) {
  const int*   ei     = (const int*)d_in[0];
  const float* embed  = (const float*)d_in[1];
  const float* W1     = (const float*)d_in[2];
  const float* a_src1 = (const float*)d_in[3];
  const float* a_dst1 = (const float*)d_in[4];
  const float* b1     = (const float*)d_in[5];
  const float* W2     = (const float*)d_in[6];
  const float* a_src2 = (const float*)d_in[7];
  const float* a_dst2 = (const float*)d_in[8];
  const float* b2     = (const float*)d_in[9];

  const int E  = in_sizes[0] / 2;
  const int H  = in_sizes[3];          // 128
  const int C  = in_sizes[2] / H;      // 256
  const int N  = in_sizes[1] / C;      // 100000
  const int Et = E + N;
  const int NB1 = (N + 1023) >> 10;    // 98
  const int NB2 = NB1 << 4;            // 1568
  const int NS  = (Et + CHUNK - 1) / CHUNK;

  auto al16 = [](size_t x) { return (x + 15) & ~(size_t)15; };
  char* p = (char*)d_ws;
  short* hb = (short*)p;         p += al16((size_t)N * 128 * 2);
  short* xb = (short*)p;         p += al16((size_t)N * 128 * 2);
  float* sv = (float*)p;         p += al16((size_t)N * 4);
  float* dv = (float*)p;         p += al16((size_t)N * 4);
  int* row_ptr = (int*)p;        p += al16((size_t)(N + 1) * 4);
  int* col = (int*)p;            p += al16((size_t)Et * 4);
  int* cnt1 = (int*)p;           // cnt1 and cnt2 contiguous for one memset
  int* cnt2 = cnt1 + NB1;        p += al16((size_t)(NB1 + NB2) * 4);
  int* binbase = (int*)p;        p += al16((size_t)NB2 * 4);
  unsigned* rec1 = (unsigned*)p; p += al16((size_t)NB1 * CAP1 * 4);
  unsigned* rec2 = (unsigned*)p; p += al16((size_t)NB2 * CAP2 * 4);
  short* Wt1 = (short*)p;        p += al16((size_t)C * H * 2);
  short* Wt2 = (short*)p;

  dim3 blk(256);

  // ---------------- weight transposes (one launch) + counter clear ----------
  transpose_cvt2<<<dim3((C*H + H*64 + 255)/256), blk, 0, stream>>>(W1, Wt1, W2, Wt2, C, H);
  hipMemsetAsync(cnt1, 0, (size_t)(NB1 + NB2) * sizeof(int), stream);

  // ---------------- fused: split1 (CSR level 1) || layer-1 GEMM --------------
  fused_split_gemm<128, 256, false><<<dim3(NS + (N + 63)/64), blk, 0, stream>>>(
      ei, E, Et, NB1, cnt1, rec1, NS, embed, Wt1, a_src1, a_dst1, hb, sv, dv, N);

  // ---------------- CSR: split2 -> scan -> binsort ----------------
  split2<<<dim3(NB1 * SEG), blk, 0, stream>>>(rec1, cnt1, cnt2, rec2);
  scan_bins<<<dim3(1), blk, 0, stream>>>(cnt2, binbase, NB2, Et, row_ptr, N);
  binsort<<<dim3(NB2), blk, 0, stream>>>(rec2, cnt2, binbase, row_ptr, col, N);

  // ---------------- layer 1 aggregate ----------------
  gat_aggregate<128,0,true><<<dim3((N + 3)/4), blk, 0, stream>>>(row_ptr, col, sv, dv,
                                                                 hb, b1, xb, N);

  // ---------------- layer 2 ----------------
  gemm_mfma<64, 128, true><<<dim3((N + 63)/64), blk, 0, stream>>>(xb, Wt2, a_src2,
                                                                  a_dst2, hb, sv, dv, N);
  gat_aggregate<64,1,false><<<dim3((N + 3)/4), blk, 0, stream>>>(row_ptr, col, sv, dv,
                                                                 hb, b2, d_out, N);
}